// Round 1
// baseline (1339.353 us; speedup 1.0000x reference)
//
#include <hip/hip_runtime.h>
#include <math.h>

// RG-LRU: B=4, L=8192, W=1024, H=8, bw=128, fp32 throughout.
#define NB 4
#define NL 8192
#define NW 1024
#define NH 8
#define BWID 128
#define POWERF 8.0f

// ---------------- K1: block-diag matmuls + gates + a / x_norm ----------------
// grid = NB*NH*NCHUNK1 blocks of 256 threads.
// Block handles (b, head h, chunk of T_CHUNK timesteps).
// Threads: m = tid>>7 selects matrix (0: w_in/gate_x, 1: w_a/gate_a),
//          j = tid&127 is the output column. Weight column lives in VGPRs
//          (loop-invariant over the chunk); x row is block-uniform -> s_load.
#define T_CHUNK 128
#define NCHUNK1 (NL / T_CHUNK) // 64

__global__ __launch_bounds__(256, 2)
void gates_kernel(const float* __restrict__ x,
                  const float* __restrict__ a_param,
                  const float* __restrict__ w_in,
                  const float* __restrict__ b_in,
                  const float* __restrict__ w_a,
                  const float* __restrict__ b_a,
                  float* __restrict__ a_out,
                  float* __restrict__ xn_out) {
  const int blk = blockIdx.x;
  const int chunk = blk % NCHUNK1;
  const int h = (blk / NCHUNK1) % NH;
  const int b = blk / (NCHUNK1 * NH);
  const int tid = threadIdx.x;
  const int m = tid >> 7;   // wave-uniform (waves 0,1 -> m=0; waves 2,3 -> m=1)
  const int j = tid & 127;
  const int ch = h * BWID + j;

  // Load this thread's weight column into registers (once per block).
  const float* wmat = (m ? w_a : w_in) + h * BWID * BWID;
  float wcol[BWID];
#pragma unroll
  for (int i = 0; i < BWID; ++i) wcol[i] = wmat[i * BWID + j];
  const float bias = (m ? b_a : b_in)[ch];
  // softplus(a_param); a_param in [-6.9, -2.2] so expf is safe
  const float sp = log1pf(expf(a_param[ch]));

  __shared__ float sh_la[BWID]; // log_a exchange (gate_a wave -> gate_x wave)

  const size_t row0 = ((size_t)b * NL + (size_t)chunk * T_CHUNK) * NW + h * BWID;

  for (int t = 0; t < T_CHUNK; ++t) {
    const float* xr = x + row0 + (size_t)t * NW; // block-uniform -> scalar loads
    float a0 = 0.f, a1 = 0.f, a2 = 0.f, a3 = 0.f;
#pragma unroll
    for (int i = 0; i < BWID; i += 4) {
      a0 = fmaf(xr[i + 0], wcol[i + 0], a0);
      a1 = fmaf(xr[i + 1], wcol[i + 1], a1);
      a2 = fmaf(xr[i + 2], wcol[i + 2], a2);
      a3 = fmaf(xr[i + 3], wcol[i + 3], a3);
    }
    const float acc = ((a0 + a1) + (a2 + a3)) + bias;
    const float gate = 1.f / (1.f + __expf(-acc)); // sigmoid

    if (m) {
      sh_la[j] = -POWERF * gate * sp; // log_a
    }
    __syncthreads();
    if (!m) {
      const float log_a = sh_la[j];
      const float av  = __expf(log_a);
      const float a2v = __expf(2.f * log_a);
      const float xv  = xr[j];
      const float xn  = xv * gate * sqrtf(fmaxf(1.f - a2v, 0.f));
      const size_t o = row0 + (size_t)t * NW + j;
      a_out[o]  = av;
      xn_out[o] = xn;
    }
    __syncthreads();
  }
}

// ---------------- chunked linear scan: h_t = a_t*h + x_t --------------------
#define C2 128
#define T2 (NL / C2) // 64

// K2: per-chunk local scan from h=0 -> (prod a, h_end). Thread = 4 channels.
__global__ void scan_local(const float* __restrict__ a_ws,
                           const float* __restrict__ xn,
                           float* __restrict__ Aprod,
                           float* __restrict__ hend) {
  const int blk = blockIdx.x; // b*C2 + c
  const int c = blk % C2;
  const int b = blk / C2;
  const int w4 = threadIdx.x; // 0..255 -> channels 4*w4..4*w4+3
  const size_t base = ((size_t)b * NL + (size_t)c * T2) * NW + 4 * w4;
  float h0 = 0.f, h1 = 0.f, h2 = 0.f, h3 = 0.f;
  float A0 = 1.f, A1 = 1.f, A2 = 1.f, A3 = 1.f;
  for (int t = 0; t < T2; ++t) {
    const float4 a  = *(const float4*)(a_ws + base + (size_t)t * NW);
    const float4 xv = *(const float4*)(xn   + base + (size_t)t * NW);
    h0 = fmaf(a.x, h0, xv.x); A0 *= a.x;
    h1 = fmaf(a.y, h1, xv.y); A1 *= a.y;
    h2 = fmaf(a.z, h2, xv.z); A2 *= a.z;
    h3 = fmaf(a.w, h3, xv.w); A3 *= a.w;
  }
  const size_t o = ((size_t)c * NB + b) * NW + 4 * w4;
  *(float4*)(Aprod + o) = make_float4(A0, A1, A2, A3);
  *(float4*)(hend  + o) = make_float4(h0, h1, h2, h3);
}

// K3: serial prefix over the C2 chunk carries -> exclusive h_init per chunk.
__global__ void scan_carry(const float* __restrict__ Aprod,
                           const float* __restrict__ hend,
                           float* __restrict__ hinit) {
  const int tid = blockIdx.x * blockDim.x + threadIdx.x; // 0..1023
  const int b  = tid >> 8;
  const int w4 = tid & 255;
  float c0 = 0.f, c1 = 0.f, c2 = 0.f, c3 = 0.f;
  for (int c = 0; c < C2; ++c) {
    const size_t o = ((size_t)c * NB + b) * NW + 4 * w4;
    *(float4*)(hinit + o) = make_float4(c0, c1, c2, c3); // exclusive
    const float4 A  = *(const float4*)(Aprod + o);
    const float4 he = *(const float4*)(hend + o);
    c0 = fmaf(A.x, c0, he.x);
    c1 = fmaf(A.y, c1, he.y);
    c2 = fmaf(A.z, c2, he.z);
    c3 = fmaf(A.w, c3, he.w);
  }
}

// K4: re-scan each chunk from its h_init, write output in place over x_norm.
__global__ void scan_final(const float* __restrict__ a_ws,
                           const float* __restrict__ hinit,
                           float* __restrict__ out) {
  const int blk = blockIdx.x; // b*C2 + c
  const int c = blk % C2;
  const int b = blk / C2;
  const int w4 = threadIdx.x;
  const size_t hidx = ((size_t)c * NB + b) * NW + 4 * w4;
  const float4 hi = *(const float4*)(hinit + hidx);
  float h0 = hi.x, h1 = hi.y, h2 = hi.z, h3 = hi.w;
  const size_t base = ((size_t)b * NL + (size_t)c * T2) * NW + 4 * w4;
  for (int t = 0; t < T2; ++t) {
    const size_t o = base + (size_t)t * NW;
    const float4 a  = *(const float4*)(a_ws + o);
    const float4 xv = *(const float4*)(out + o);
    h0 = fmaf(a.x, h0, xv.x);
    h1 = fmaf(a.y, h1, xv.y);
    h2 = fmaf(a.z, h2, xv.z);
    h3 = fmaf(a.w, h3, xv.w);
    *(float4*)(out + o) = make_float4(h0, h1, h2, h3);
  }
}

extern "C" void kernel_launch(void* const* d_in, const int* in_sizes, int n_in,
                              void* d_out, int out_size, void* d_ws, size_t ws_size,
                              hipStream_t stream) {
  const float* x       = (const float*)d_in[0];
  const float* a_param = (const float*)d_in[1];
  const float* w_in    = (const float*)d_in[2];
  const float* b_in    = (const float*)d_in[3];
  const float* w_a     = (const float*)d_in[4];
  const float* b_a     = (const float*)d_in[5];
  float* out = (float*)d_out;

  // Workspace: a array (B*L*W floats = 128 MB) + 3 small carry arrays (2 MB ea).
  float* a_ws  = (float*)d_ws;
  float* Aprod = a_ws + (size_t)NB * NL * NW;
  float* hend  = Aprod + (size_t)C2 * NB * NW;
  float* hinit = hend  + (size_t)C2 * NB * NW;

  gates_kernel<<<NB * NH * NCHUNK1, 256, 0, stream>>>(
      x, a_param, w_in, b_in, w_a, b_a, a_ws, out);
  scan_local<<<NB * C2, 256, 0, stream>>>(a_ws, out, Aprod, hend);
  scan_carry<<<4, 256, 0, stream>>>(Aprod, hend, hinit);
  scan_final<<<NB * C2, 256, 0, stream>>>(a_ws, hinit, out);
}

// Round 2
// 548.152 us; speedup vs baseline: 2.4434x; 2.4434x over previous
//
#include <hip/hip_runtime.h>
#include <math.h>

// RG-LRU: B=4, L=8192, W=1024, H=8, bw=128, fp32 throughout.
#define NB 4
#define NL 8192
#define NW 1024
#define NH 8
#define BWID 128
#define POWERF 8.0f

// ---------------- K1: block-diag matmuls + gates + a / x_norm ----------------
// Register-tiled vector-fp32 GEMM. Block = (b, head, TM=64 timesteps).
// LDS: X tile [64][128] (32 KB, staged once) + k-tiles of W_in/W_a
// ([KT=32][128], 16 KB each). Thread (tc=tid&31, tr=tid>>5) computes an
// 8-row x 4-col output patch for BOTH matrices (64 fp32 accumulators in
// VGPRs -- small fixed arrays, fully unrolled, no spill). Per k:
// 2x ds_read_b128 (W) + 8 broadcast ds_read_b32 (X) -> 64 independent FMAs.
#define TM 64
#define KT 32
#define NRC (NL / TM) // 128 row-chunks

__global__ __launch_bounds__(256, 2)
void gates_kernel(const float* __restrict__ x,
                  const float* __restrict__ a_param,
                  const float* __restrict__ w_in,
                  const float* __restrict__ b_in,
                  const float* __restrict__ w_a,
                  const float* __restrict__ b_a,
                  float* __restrict__ a_out,
                  float* __restrict__ xn_out) {
  __shared__ float sX[TM * BWID];    // 32 KB, lives whole block
  __shared__ float sWin[KT * BWID];  // 16 KB, per k-tile
  __shared__ float sWa[KT * BWID];   // 16 KB, per k-tile

  const int blk = blockIdx.x;
  const int rc = blk % NRC;
  const int h  = (blk / NRC) % NH;
  const int b  = blk / (NRC * NH);
  const int tid = threadIdx.x;
  const int tc = tid & 31;   // col group: cols c0..c0+3
  const int tr = tid >> 5;   // row group: rows r0..r0+7
  const int c0 = tc * 4;
  const int r0 = tr * 8;

  const size_t xbase = ((size_t)b * NL + (size_t)rc * TM) * NW + h * BWID;

  // ---- stage X tile [TM][BWID]: 2048 float4, 8 per thread, coalesced ----
#pragma unroll
  for (int i = 0; i < 8; ++i) {
    const int idx = tid + 256 * i;     // float4 index
    const int row = idx >> 5;
    const int c4  = (idx & 31) * 4;
    const float4 v = *(const float4*)(x + xbase + (size_t)row * NW + c4);
    *(float4*)(sX + row * BWID + c4) = v;
  }

  float accx[8][4], acca[8][4];
#pragma unroll
  for (int rr = 0; rr < 8; ++rr)
#pragma unroll
    for (int cc = 0; cc < 4; ++cc) { accx[rr][cc] = 0.f; acca[rr][cc] = 0.f; }

  const float* winp = w_in + h * BWID * BWID;
  const float* wap  = w_a  + h * BWID * BWID;

#pragma unroll 1
  for (int kt = 0; kt < BWID; kt += KT) {
    __syncthreads(); // X staged (kt=0) / previous W tile consumed (kt>0)
    // ---- stage W k-tile: 1024 float4 per matrix, 4 per thread ----
#pragma unroll
    for (int i = 0; i < 4; ++i) {
      const int idx = tid + 256 * i;
      const int k  = idx >> 5;
      const int j4 = (idx & 31) * 4;
      *(float4*)(sWin + k * BWID + j4) =
          *(const float4*)(winp + (size_t)(kt + k) * BWID + j4);
      *(float4*)(sWa + k * BWID + j4) =
          *(const float4*)(wap + (size_t)(kt + k) * BWID + j4);
    }
    __syncthreads();

#pragma unroll 8
    for (int k = 0; k < KT; ++k) {
      const float4 win = *(const float4*)(sWin + k * BWID + c0);
      const float4 wa  = *(const float4*)(sWa  + k * BWID + c0);
      float xv[8];
#pragma unroll
      for (int rr = 0; rr < 8; ++rr) xv[rr] = sX[(r0 + rr) * BWID + kt + k];
#pragma unroll
      for (int rr = 0; rr < 8; ++rr) {
        accx[rr][0] = fmaf(xv[rr], win.x, accx[rr][0]);
        accx[rr][1] = fmaf(xv[rr], win.y, accx[rr][1]);
        accx[rr][2] = fmaf(xv[rr], win.z, accx[rr][2]);
        accx[rr][3] = fmaf(xv[rr], win.w, accx[rr][3]);
        acca[rr][0] = fmaf(xv[rr], wa.x, acca[rr][0]);
        acca[rr][1] = fmaf(xv[rr], wa.y, acca[rr][1]);
        acca[rr][2] = fmaf(xv[rr], wa.z, acca[rr][2]);
        acca[rr][3] = fmaf(xv[rr], wa.w, acca[rr][3]);
      }
    }
  }

  // ---- epilogue: both gates in-register, no cross-thread exchange ----
  const float4 bx4 = *(const float4*)(b_in + h * BWID + c0);
  const float4 ba4 = *(const float4*)(b_a + h * BWID + c0);
  const float4 ap4 = *(const float4*)(a_param + h * BWID + c0);
  float bx[4] = {bx4.x, bx4.y, bx4.z, bx4.w};
  float ba[4] = {ba4.x, ba4.y, ba4.z, ba4.w};
  float sp[4] = {log1pf(expf(ap4.x)), log1pf(expf(ap4.y)),
                 log1pf(expf(ap4.z)), log1pf(expf(ap4.w))};

#pragma unroll
  for (int rr = 0; rr < 8; ++rr) {
    const float4 xrow = *(const float4*)(sX + (r0 + rr) * BWID + c0);
    const float xvv[4] = {xrow.x, xrow.y, xrow.z, xrow.w};
    float av[4], xnv[4];
#pragma unroll
    for (int cc = 0; cc < 4; ++cc) {
      const float zx = accx[rr][cc] + bx[cc];
      const float za = acca[rr][cc] + ba[cc];
      const float gx = __builtin_amdgcn_rcpf(1.f + __expf(-zx));
      const float ga = __builtin_amdgcn_rcpf(1.f + __expf(-za));
      const float la = -POWERF * ga * sp[cc];
      av[cc] = __expf(la);
      const float asq = __expf(2.f * la);
      xnv[cc] = xvv[cc] * gx * sqrtf(fmaxf(1.f - asq, 0.f));
    }
    const size_t o = xbase + (size_t)(r0 + rr) * NW + c0;
    *(float4*)(a_out + o)  = make_float4(av[0], av[1], av[2], av[3]);
    *(float4*)(xn_out + o) = make_float4(xnv[0], xnv[1], xnv[2], xnv[3]);
  }
}

// ---------------- chunked linear scan: h_t = a_t*h + x_t --------------------
#define C2 128
#define T2 (NL / C2) // 64

// K2: per-chunk local scan from h=0 -> (prod a, h_end).
// 512 threads/block, float2/thread -> 8 waves/block for latency hiding.
__global__ void scan_local(const float* __restrict__ a_ws,
                           const float* __restrict__ xn,
                           float* __restrict__ Aprod,
                           float* __restrict__ hend) {
  const int blk = blockIdx.x; // b*C2 + c
  const int c = blk % C2;
  const int b = blk / C2;
  const int w2 = threadIdx.x; // 0..511 -> channels 2*w2, 2*w2+1
  const size_t base = ((size_t)b * NL + (size_t)c * T2) * NW + 2 * w2;
  float h0 = 0.f, h1 = 0.f, A0 = 1.f, A1 = 1.f;
#pragma unroll 4
  for (int t = 0; t < T2; ++t) {
    const float2 a  = *(const float2*)(a_ws + base + (size_t)t * NW);
    const float2 xv = *(const float2*)(xn   + base + (size_t)t * NW);
    h0 = fmaf(a.x, h0, xv.x); A0 *= a.x;
    h1 = fmaf(a.y, h1, xv.y); A1 *= a.y;
  }
  const size_t o = ((size_t)c * NB + b) * NW + 2 * w2;
  *(float2*)(Aprod + o) = make_float2(A0, A1);
  *(float2*)(hend  + o) = make_float2(h0, h1);
}

// K3: serial prefix over the C2 chunk carries -> exclusive h_init per chunk.
__global__ void scan_carry(const float* __restrict__ Aprod,
                           const float* __restrict__ hend,
                           float* __restrict__ hinit) {
  const int tid = blockIdx.x * blockDim.x + threadIdx.x; // 0..1023
  const int b  = tid >> 8;
  const int w4 = tid & 255;
  float c0 = 0.f, c1 = 0.f, c2 = 0.f, c3 = 0.f;
  for (int c = 0; c < C2; ++c) {
    const size_t o = ((size_t)c * NB + b) * NW + 4 * w4;
    *(float4*)(hinit + o) = make_float4(c0, c1, c2, c3); // exclusive
    const float4 A  = *(const float4*)(Aprod + o);
    const float4 he = *(const float4*)(hend + o);
    c0 = fmaf(A.x, c0, he.x);
    c1 = fmaf(A.y, c1, he.y);
    c2 = fmaf(A.z, c2, he.z);
    c3 = fmaf(A.w, c3, he.w);
  }
}

// K4: re-scan each chunk from its h_init, write output in place over x_norm.
__global__ void scan_final(const float* __restrict__ a_ws,
                           const float* __restrict__ hinit,
                           float* __restrict__ out) {
  const int blk = blockIdx.x; // b*C2 + c
  const int c = blk % C2;
  const int b = blk / C2;
  const int w2 = threadIdx.x; // 0..511
  const size_t hidx = ((size_t)c * NB + b) * NW + 2 * w2;
  const float2 hi = *(const float2*)(hinit + hidx);
  float h0 = hi.x, h1 = hi.y;
  const size_t base = ((size_t)b * NL + (size_t)c * T2) * NW + 2 * w2;
#pragma unroll 4
  for (int t = 0; t < T2; ++t) {
    const size_t o = base + (size_t)t * NW;
    const float2 a  = *(const float2*)(a_ws + o);
    const float2 xv = *(const float2*)(out + o);
    h0 = fmaf(a.x, h0, xv.x);
    h1 = fmaf(a.y, h1, xv.y);
    *(float2*)(out + o) = make_float2(h0, h1);
  }
}

extern "C" void kernel_launch(void* const* d_in, const int* in_sizes, int n_in,
                              void* d_out, int out_size, void* d_ws, size_t ws_size,
                              hipStream_t stream) {
  const float* x       = (const float*)d_in[0];
  const float* a_param = (const float*)d_in[1];
  const float* w_in    = (const float*)d_in[2];
  const float* b_in    = (const float*)d_in[3];
  const float* w_a     = (const float*)d_in[4];
  const float* b_a     = (const float*)d_in[5];
  float* out = (float*)d_out;

  // Workspace: a array (128 MB) + 3 carry arrays (2 MB each).
  float* a_ws  = (float*)d_ws;
  float* Aprod = a_ws + (size_t)NB * NL * NW;
  float* hend  = Aprod + (size_t)C2 * NB * NW;
  float* hinit = hend  + (size_t)C2 * NB * NW;

  gates_kernel<<<NB * NH * NRC, 256, 0, stream>>>(
      x, a_param, w_in, b_in, w_a, b_a, a_ws, out);
  scan_local<<<NB * C2, 512, 0, stream>>>(a_ws, out, Aprod, hend);
  scan_carry<<<4, 256, 0, stream>>>(Aprod, hend, hinit);
  scan_final<<<NB * C2, 512, 0, stream>>>(a_ws, hinit, out);
}